// Round 11
// baseline (180.430 us; speedup 1.0000x reference)
//
#include <hip/hip_runtime.h>
#include <math.h>

// Problem constants: B=1, T=384, C=512, H=8, D=64, E=16. Inputs/outputs f32.
#define TT 384
#define CC 512
#define HH 8
#define EE 16

typedef __bf16 bf16_t;
typedef __bf16 bf16x8 __attribute__((ext_vector_type(8)));
typedef __bf16 bf16x4v __attribute__((ext_vector_type(4)));
typedef float f32x4 __attribute__((ext_vector_type(4)));

__device__ __forceinline__ float wave_reduce_sum(float v) {
#pragma unroll
  for (int off = 32; off >= 1; off >>= 1) v += __shfl_xor(v, off, 64);
  return v;
}

// ---------------------------------------------------------------------------
// wrow_unit: one LN-folded weight row: W'[n]=g∘W[n] (bf16), s1[n]=Σ W'[n,k],
// c[n] = Σ b_k W[n,k] + extra
// ---------------------------------------------------------------------------
__device__ __forceinline__ void wrow_unit(const float* __restrict__ wr,
                                          const float* __restrict__ g,
                                          const float* __restrict__ bb,
                                          float extra_c, bf16_t* __restrict__ orow,
                                          float* __restrict__ s1p,
                                          float* __restrict__ cp, int lane) {
  const float* p = wr + lane * 8;
  f32x4 w0 = *(const f32x4*)p, w1 = *(const f32x4*)(p + 4);
  f32x4 g0 = *(const f32x4*)(g + lane * 8), g1 = *(const f32x4*)(g + lane * 8 + 4);
  f32x4 b0 = *(const f32x4*)(bb + lane * 8), b1 = *(const f32x4*)(bb + lane * 8 + 4);
  f32x4 p0 = w0 * g0, p1 = w1 * g1;
  bf16x8 o;
  o[0] = (bf16_t)p0.x; o[1] = (bf16_t)p0.y; o[2] = (bf16_t)p0.z; o[3] = (bf16_t)p0.w;
  o[4] = (bf16_t)p1.x; o[5] = (bf16_t)p1.y; o[6] = (bf16_t)p1.z; o[7] = (bf16_t)p1.w;
  *(bf16x8*)(orow + lane * 8) = o;
  float s1 = p0.x + p0.y + p0.z + p0.w + p1.x + p1.y + p1.z + p1.w;
  float c = w0.x * b0.x + w0.y * b0.y + w0.z * b0.z + w0.w * b0.w +
            w1.x * b1.x + w1.y * b1.y + w1.z * b1.z + w1.w * b1.w;
  s1 = wave_reduce_sum(s1);
  c = wave_reduce_sum(c);
  if (lane == 0) { *s1p = s1; *cp = c + extra_c; }
}

// ---------------------------------------------------------------------------
// pre_k (1569 blocks): [0,256) edge tables; [256,640) qkv W' rows;
// [640,1152) fc W' rows; [1152,1216) proj conv; [1216,1472) cproj conv;
// [1472,1568) x row stats; [1568] zero x1 stat accumulators.
// ---------------------------------------------------------------------------
struct PreArgs {
  const float *x, *ln1w, *ln1b, *wattn, *wattnb, *eemb, *wekw, *wekb, *wevw,
      *wevb, *ln2w, *ln2b, *cfcw, *cfcb, *wproj, *wcproj;
  float *ektab, *evtab, *xmu, *xrs, *x1s1, *x1s2, *s1q, *cq, *s1f, *cf;
  bf16_t *wqkv_bf, *wfc_bf, *wproj_bf, *wcproj_bf;
};

__global__ __launch_bounds__(256) void pre_k(PreArgs P) {
  int b = blockIdx.x, tid = threadIdx.x, lane = tid & 63, wave = tid >> 6;
  if (b < 256) {
    int wid = b * 4 + wave;  // 0..1023
    int gbase = wid * 16;
    int table = gbase >> 13;
    int e = (gbase >> 9) & 15;
    int c0 = gbase & 511;
    const float* er = P.eemb + e * 512 + lane * 8;
    f32x4 ea = *(const f32x4*)er;
    f32x4 eb = *(const f32x4*)(er + 4);
    const float* wbase = table ? P.wevw : P.wekw;
    const float* bbase = table ? P.wevb : P.wekb;
    float* obase = (table ? P.evtab : P.ektab) + e * 512;
#pragma unroll
    for (int o = 0; o < 16; o++) {
      int c = c0 + o;
      const float* wr = wbase + (size_t)c * 512 + lane * 8;
      f32x4 wa = *(const f32x4*)wr;
      f32x4 wb = *(const f32x4*)(wr + 4);
      float acc = ea.x * wa.x + ea.y * wa.y + ea.z * wa.z + ea.w * wa.w +
                  eb.x * wb.x + eb.y * wb.y + eb.z * wb.z + eb.w * wb.w;
      acc = wave_reduce_sum(acc);
      if (lane == 0) obase[c] = acc + bbase[c];
    }
  } else if (b < 640) {
    int n = (b - 256) * 4 + wave;  // 0..1535
    wrow_unit(P.wattn + (size_t)n * 512, P.ln1w, P.ln1b, P.wattnb[n],
              P.wqkv_bf + (size_t)n * 512, P.s1q + n, P.cq + n, lane);
  } else if (b < 1152) {
    int n = (b - 640) * 4 + wave;  // 0..2047
    wrow_unit(P.cfcw + (size_t)n * 512, P.ln2w, P.ln2b, P.cfcb[n],
              P.wfc_bf + (size_t)n * 512, P.s1f + n, P.cf + n, lane);
  } else if (b < 1216) {
    int base = (b - 1152) * 1024;
    for (int u = tid; u < 1024; u += 256) {
      f32x4 a = *((const f32x4*)P.wproj + base + u);
      bf16x4v o;
      o[0] = (bf16_t)a.x; o[1] = (bf16_t)a.y; o[2] = (bf16_t)a.z; o[3] = (bf16_t)a.w;
      *((bf16x4v*)P.wproj_bf + base + u) = o;
    }
  } else if (b < 1472) {
    int base = (b - 1216) * 1024;
    for (int u = tid; u < 1024; u += 256) {
      f32x4 a = *((const f32x4*)P.wcproj + base + u);
      bf16x4v o;
      o[0] = (bf16_t)a.x; o[1] = (bf16_t)a.y; o[2] = (bf16_t)a.z; o[3] = (bf16_t)a.w;
      *((bf16x4v*)P.wcproj_bf + base + u) = o;
    }
  } else if (b < 1568) {
    int r = (b - 1472) * 4 + wave;  // 0..383
    const float* xr = P.x + (size_t)r * 512 + lane * 8;
    f32x4 a = *(const f32x4*)xr, c = *(const f32x4*)(xr + 4);
    float s = a.x + a.y + a.z + a.w + c.x + c.y + c.z + c.w;
    float q = a.x * a.x + a.y * a.y + a.z * a.z + a.w * a.w +
              c.x * c.x + c.y * c.y + c.z * c.z + c.w * c.w;
    s = wave_reduce_sum(s);
    q = wave_reduce_sum(q);
    if (lane == 0) {
      float mu = s * (1.0f / 512.0f);
      float var = q * (1.0f / 512.0f) - mu * mu;
      P.xmu[r] = mu;
      P.xrs[r] = rsqrtf(var + 1e-5f);
    }
  } else {
    for (int i = tid; i < 384; i += 256) { P.x1s1[i] = 0.f; P.x1s2[i] = 0.f; }
  }
}

// ---------------------------------------------------------------------------
// Split-K NT GEMM, 16x32 tile (was 32x32 — doubled block count for TLP in
// the latency-bound regime; R4/R7/R8 law: more blocks wins). 4 waves each
// K/4; K-loop hoists 4 k-steps of loads before MFMA.
// MODE 0 (QKV): A=x f32; fused-LN epilogue ->bf16
// MODE 1 (PROJ): A bf16, +bias +res ->f32, atomic row stats of result
// MODE 2 (FC):   A=x1 f32, row stats from S1/S2; fused-LN; gelu ->bf16
// MODE 3 (CPROJ):A bf16, +bias +res ->f32 (d_out)
// ---------------------------------------------------------------------------
template <int MODE>
__global__ __launch_bounds__(256) void gemm_k(
    const void* __restrict__ Aptr, const bf16_t* __restrict__ Wb,
    const float* __restrict__ e0, const float* __restrict__ e1,
    const float* __restrict__ e2, const float* __restrict__ e3,
    const float* __restrict__ res, void* __restrict__ out,
    float* __restrict__ st1, float* __restrict__ st2, int N, int K) {
  constexpr bool AF32 = (MODE == 0 || MODE == 2);
  constexpr int AW = AF32 ? 2 : 1;
  __shared__ float part[4][16][32];  // 8 KB
  int tid = threadIdx.x;
  int lane = tid & 63, wave = tid >> 6;
  int m0 = blockIdx.y * 16, n0 = blockIdx.x * 32;
  int r16 = lane & 15, quad = lane >> 4;
  int kchunk = K >> 2, k0 = wave * kchunk;

  f32x4 acc[2];
  f32x4 zero = {0.f, 0.f, 0.f, 0.f};
  acc[0] = zero;
  acc[1] = zero;

  const float* Af = (const float*)Aptr + (size_t)(m0 + r16) * K + k0 + quad * 8;
  const bf16_t* Ab = (const bf16_t*)Aptr + (size_t)(m0 + r16) * K + k0 + quad * 8;
  const bf16_t* Wp = Wb + (size_t)(n0 + r16) * K + k0 + quad * 8;

  for (int kb0 = 0; kb0 < kchunk; kb0 += 128) {  // 4 k-steps per group
    uint4 araw[4][AW];
    uint4 braw[4][2];
    // ---- stage ALL loads first (12-16 independent loads in flight)
#pragma unroll
    for (int u = 0; u < 4; u++) {
      int kb = kb0 + u * 32;
      if (AF32) {
        araw[u][0] = *(const uint4*)(Af + kb);
        araw[u][1] = *(const uint4*)(Af + kb + 4);
      } else {
        araw[u][0] = *(const uint4*)(Ab + kb);
      }
      braw[u][0] = *(const uint4*)(Wp + kb);
      braw[u][1] = *(const uint4*)(Wp + (size_t)16 * K + kb);
    }
    // ---- convert + MFMA
#pragma unroll
    for (int u = 0; u < 4; u++) {
      bf16x8 af, bfr[2];
      if (AF32) {
        f32x4 a = *reinterpret_cast<const f32x4*>(&araw[u][0]);
        f32x4 c = *reinterpret_cast<const f32x4*>(&araw[u][1]);
        af[0] = (bf16_t)a.x; af[1] = (bf16_t)a.y;
        af[2] = (bf16_t)a.z; af[3] = (bf16_t)a.w;
        af[4] = (bf16_t)c.x; af[5] = (bf16_t)c.y;
        af[6] = (bf16_t)c.z; af[7] = (bf16_t)c.w;
      } else {
        af = *reinterpret_cast<const bf16x8*>(&araw[u][0]);
      }
      bfr[0] = *reinterpret_cast<const bf16x8*>(&braw[u][0]);
      bfr[1] = *reinterpret_cast<const bf16x8*>(&braw[u][1]);
#pragma unroll
      for (int j = 0; j < 2; j++)
        acc[j] = __builtin_amdgcn_mfma_f32_16x16x32_bf16(af, bfr[j], acc[j],
                                                         0, 0, 0);
    }
  }

#pragma unroll
  for (int j = 0; j < 2; j++)
#pragma unroll
    for (int r = 0; r < 4; r++)
      part[wave][quad * 4 + r][j * 16 + r16] = acc[j][r];
  __syncthreads();

  if (tid < 128) {
    int row = tid >> 3, c4 = (tid & 7) * 4;
    f32x4 v = *(const f32x4*)&part[0][row][c4];
    v += *(const f32x4*)&part[1][row][c4];
    v += *(const f32x4*)&part[2][row][c4];
    v += *(const f32x4*)&part[3][row][c4];
    int grow = m0 + row, gcol = n0 + c4;

    if (MODE == 0 || MODE == 2) {
      float mu, rs;
      if (MODE == 0) {
        mu = e0[grow]; rs = e1[grow];
      } else {
        float S = e0[grow], Q = e1[grow];
        mu = S * (1.0f / 512.0f);
        float var = Q * (1.0f / 512.0f) - mu * mu;
        rs = rsqrtf(var + 1e-5f);
      }
      f32x4 s1v = *(const f32x4*)(e2 + gcol);
      f32x4 ccv = *(const f32x4*)(e3 + gcol);
#pragma unroll
      for (int t = 0; t < 4; t++) {
        float x = rs * (v[t] - mu * s1v[t]) + ccv[t];
        if (MODE == 2) x = 0.5f * x * (1.0f + erff(x * 0.70710678118654752f));
        v[t] = x;
      }
      bf16x4v o;
#pragma unroll
      for (int t = 0; t < 4; t++) o[t] = (bf16_t)v[t];
      *(bf16x4v*)((bf16_t*)out + (size_t)grow * N + gcol) = o;
    } else {
      v += *(const f32x4*)(e2 + gcol);  // bias
      v += *(const f32x4*)(res + (size_t)grow * N + gcol);
      *(f32x4*)((float*)out + (size_t)grow * N + gcol) = v;
      if (MODE == 1) {
        float sv = v.x + v.y + v.z + v.w;
        float qv = v.x * v.x + v.y * v.y + v.z * v.z + v.w * v.w;
        sv += __shfl_down(sv, 4, 8); qv += __shfl_down(qv, 4, 8);
        sv += __shfl_down(sv, 2, 8); qv += __shfl_down(qv, 2, 8);
        sv += __shfl_down(sv, 1, 8); qv += __shfl_down(qv, 1, 8);
        if ((tid & 7) == 0) {
          atomicAdd(st1 + grow, sv);
          atomicAdd(st2 + grow, qv);
        }
      }
    }
  }
}

// ---------------------------------------------------------------------------
// Attention: one block per (query row i, head h), 3072 blocks, ascending i.
// No-max softmax (scores bounded: 0.02-scale weights), 2-deep PV. R10 exact
// form — measured best; do not touch without per-dispatch evidence.
// ---------------------------------------------------------------------------
__global__ __launch_bounds__(256) void attn_k(
    const bf16_t* __restrict__ qkv, const int* __restrict__ bias_matrix,
    const float* __restrict__ attn_bias_emb, const float* __restrict__ ek_tab,
    const float* __restrict__ ev_tab, bf16_t* __restrict__ ybuf) {
  __shared__ float s[TT];
  __shared__ int ebuf[TT];
  __shared__ float qe[EE][68];
  __shared__ float evh[EE * 64];
  __shared__ float red[4 * 64];
  __shared__ float absh[EE];
  __shared__ float scr[4];

  int i = blockIdx.x, h = blockIdx.y;
  int tid = threadIdx.x, lane = tid & 63, wave = tid >> 6;
  int n = i + 1;

  for (int j = tid; j < n; j += 256) ebuf[j] = bias_matrix[i * TT + j];
  if (tid < EE) absh[tid] = attn_bias_emb[tid * HH + h];
  for (int idx = tid; idx < EE * 64; idx += 256) {
    int e = idx >> 6, d = idx & 63;
    float qv = (float)qkv[(size_t)i * 1536 + h * 64 + d];
    qe[e][d] = qv * ek_tab[e * 512 + h * 64 + d];
    evh[idx] = ev_tab[e * 512 + h * 64 + d];
  }
  __syncthreads();

  // ---- scores + exp (no max pass), accumulate denominator
  float ls = 0.0f;
  for (int jl = tid; jl < n; jl += 256) {
    int e = ebuf[jl];
    const uint4* kp = (const uint4*)(qkv + (size_t)jl * 1536 + 512 + h * 64);
    uint4 kr[8];
#pragma unroll
    for (int dg = 0; dg < 8; dg++) kr[dg] = kp[dg];
    float acc = 0.f;
#pragma unroll
    for (int dg = 0; dg < 8; dg++) {
      bf16x8 kv = *reinterpret_cast<const bf16x8*>(&kr[dg]);
      f32x4 qa = *(const f32x4*)&qe[e][dg * 8];
      f32x4 qb = *(const f32x4*)&qe[e][dg * 8 + 4];
      acc += (float)kv[0] * qa.x + (float)kv[1] * qa.y + (float)kv[2] * qa.z +
             (float)kv[3] * qa.w + (float)kv[4] * qb.x + (float)kv[5] * qb.y +
             (float)kv[6] * qb.z + (float)kv[7] * qb.w;
    }
    float p = __expf(acc * 0.125f + absh[e]);
    s[jl] = p;
    ls += p;
  }
  ls = wave_reduce_sum(ls);
  if (lane == 0) scr[wave] = ls;
  __syncthreads();
  float inv = 1.0f / (scr[0] + scr[1] + scr[2] + scr[3]);

  // ---- PV: wave per j, lane per d (2-deep — measured best, R6)
  float acc = 0.0f;
  int j = wave;
  for (; j + 4 < n; j += 8) {
    int e0 = ebuf[j], e1 = ebuf[j + 4];
    float p0 = s[j], p1 = s[j + 4];
    float v0 = (float)qkv[(size_t)j * 1536 + 1024 + h * 64 + lane];
    float v1 = (float)qkv[(size_t)(j + 4) * 1536 + 1024 + h * 64 + lane];
    acc += p0 * v0 * evh[e0 * 64 + lane] + p1 * v1 * evh[e1 * 64 + lane];
  }
  for (; j < n; j += 4) {
    int e = ebuf[j];
    float vv = (float)qkv[(size_t)j * 1536 + 1024 + h * 64 + lane];
    acc += s[j] * vv * evh[e * 64 + lane];
  }
  red[wave * 64 + lane] = acc;
  __syncthreads();
  if (tid < 64) {
    float y = (red[tid] + red[64 + tid] + red[128 + tid] + red[192 + tid]) * inv;
    ybuf[(size_t)i * CC + h * 64 + tid] = (bf16_t)y;
  }
}

// ---------------------------------------------------------------------------
extern "C" void kernel_launch(void* const* d_in, const int* in_sizes, int n_in,
                              void* d_out, int out_size, void* d_ws,
                              size_t ws_size, hipStream_t stream) {
  const float* x = (const float*)d_in[0];
  const int* bias_mat = (const int*)d_in[1];

  char* wp = (char*)d_ws;
  float* ektab = (float*)wp;  wp += 16 * 512 * 4;
  float* evtab = (float*)wp;  wp += 16 * 512 * 4;
  float* xmu = (float*)wp;    wp += 384 * 4;
  float* xrs = (float*)wp;    wp += 384 * 4;
  float* x1s1 = (float*)wp;   wp += 384 * 4;
  float* x1s2 = (float*)wp;   wp += 384 * 4;
  float* s1q = (float*)wp;    wp += 1536 * 4;
  float* cq = (float*)wp;     wp += 1536 * 4;
  float* s1f = (float*)wp;    wp += 2048 * 4;
  float* cf = (float*)wp;     wp += 2048 * 4;
  float* x1 = (float*)wp;     wp += 384 * 512 * 4;
  bf16_t* wqkv_bf = (bf16_t*)wp;   wp += 1536 * 512 * 2;
  bf16_t* wfc_bf = (bf16_t*)wp;    wp += 2048 * 512 * 2;
  bf16_t* wproj_bf = (bf16_t*)wp;  wp += 512 * 512 * 2;
  bf16_t* wcproj_bf = (bf16_t*)wp; wp += 512 * 2048 * 2;
  bf16_t* qkv = (bf16_t*)wp;  wp += 384 * 1536 * 2;
  bf16_t* ybuf = (bf16_t*)wp; wp += 384 * 512 * 2;
  bf16_t* gbuf = (bf16_t*)wp; wp += 384 * 2048 * 2;

  PreArgs P;
  P.x = x;
  P.ln1w = (const float*)d_in[2];
  P.ln1b = (const float*)d_in[3];
  P.wattn = (const float*)d_in[4];
  P.wattnb = (const float*)d_in[5];
  P.eemb = (const float*)d_in[9];
  P.wekw = (const float*)d_in[10];
  P.wekb = (const float*)d_in[11];
  P.wevw = (const float*)d_in[12];
  P.wevb = (const float*)d_in[13];
  P.ln2w = (const float*)d_in[14];
  P.ln2b = (const float*)d_in[15];
  P.cfcw = (const float*)d_in[16];
  P.cfcb = (const float*)d_in[17];
  P.wproj = (const float*)d_in[6];
  P.wcproj = (const float*)d_in[18];
  P.ektab = ektab; P.evtab = evtab; P.xmu = xmu; P.xrs = xrs;
  P.x1s1 = x1s1; P.x1s2 = x1s2; P.s1q = s1q; P.cq = cq; P.s1f = s1f; P.cf = cf;
  P.wqkv_bf = wqkv_bf; P.wfc_bf = wfc_bf; P.wproj_bf = wproj_bf;
  P.wcproj_bf = wcproj_bf;

  // 1) tables + all weight prep + x stats + stat zeroing
  pre_k<<<1569, 256, 0, stream>>>(P);
  // 2) qkv = LN1(x) @ wattn^T + b   (16x32 tiles, 1152 blocks)
  gemm_k<0><<<dim3(48, 24), 256, 0, stream>>>(x, wqkv_bf, xmu, xrs, s1q, cq,
                                              nullptr, qkv, nullptr, nullptr,
                                              1536, 512);
  // 3) attention (R10 exact form)
  attn_k<<<dim3(TT, HH), 256, 0, stream>>>(qkv, bias_mat,
                                           (const float*)d_in[8], ektab, evtab,
                                           ybuf);
  // 4) x1 = x + y @ wproj^T + b ; x1 row stats  (384 blocks)
  gemm_k<1><<<dim3(16, 24), 256, 0, stream>>>(
      ybuf, wproj_bf, nullptr, nullptr, (const float*)d_in[7], nullptr, x, x1,
      x1s1, x1s2, 512, 512);
  // 5) g = gelu(LN2(x1) @ cfc^T + b)  (1536 blocks)
  gemm_k<2><<<dim3(64, 24), 256, 0, stream>>>(x1, wfc_bf, x1s1, x1s2, s1f, cf,
                                              nullptr, gbuf, nullptr, nullptr,
                                              2048, 512);
  // 6) out = x1 + g @ cproj^T + b  (384 blocks)
  gemm_k<3><<<dim3(16, 24), 256, 0, stream>>>(
      gbuf, wcproj_bf, nullptr, nullptr, (const float*)d_in[19], nullptr, x1,
      d_out, nullptr, nullptr, 512, 2048);
}

// Round 12
// 174.843 us; speedup vs baseline: 1.0320x; 1.0320x over previous
//
#include <hip/hip_runtime.h>
#include <math.h>

// Problem constants: B=1, T=384, C=512, H=8, D=64, E=16. Inputs/outputs f32.
#define TT 384
#define CC 512
#define HH 8
#define EE 16

typedef __bf16 bf16_t;
typedef __bf16 bf16x8 __attribute__((ext_vector_type(8)));
typedef __bf16 bf16x4v __attribute__((ext_vector_type(4)));
typedef float f32x4 __attribute__((ext_vector_type(4)));

__device__ __forceinline__ float wave_reduce_sum(float v) {
#pragma unroll
  for (int off = 32; off >= 1; off >>= 1) v += __shfl_xor(v, off, 64);
  return v;
}

// ---------------------------------------------------------------------------
// wrow_unit: one LN-folded weight row: W'[n]=g∘W[n] (bf16), s1[n]=Σ W'[n,k],
// c[n] = Σ b_k W[n,k] + extra
// ---------------------------------------------------------------------------
__device__ __forceinline__ void wrow_unit(const float* __restrict__ wr,
                                          const float* __restrict__ g,
                                          const float* __restrict__ bb,
                                          float extra_c, bf16_t* __restrict__ orow,
                                          float* __restrict__ s1p,
                                          float* __restrict__ cp, int lane) {
  const float* p = wr + lane * 8;
  f32x4 w0 = *(const f32x4*)p, w1 = *(const f32x4*)(p + 4);
  f32x4 g0 = *(const f32x4*)(g + lane * 8), g1 = *(const f32x4*)(g + lane * 8 + 4);
  f32x4 b0 = *(const f32x4*)(bb + lane * 8), b1 = *(const f32x4*)(bb + lane * 8 + 4);
  f32x4 p0 = w0 * g0, p1 = w1 * g1;
  bf16x8 o;
  o[0] = (bf16_t)p0.x; o[1] = (bf16_t)p0.y; o[2] = (bf16_t)p0.z; o[3] = (bf16_t)p0.w;
  o[4] = (bf16_t)p1.x; o[5] = (bf16_t)p1.y; o[6] = (bf16_t)p1.z; o[7] = (bf16_t)p1.w;
  *(bf16x8*)(orow + lane * 8) = o;
  float s1 = p0.x + p0.y + p0.z + p0.w + p1.x + p1.y + p1.z + p1.w;
  float c = w0.x * b0.x + w0.y * b0.y + w0.z * b0.z + w0.w * b0.w +
            w1.x * b1.x + w1.y * b1.y + w1.z * b1.z + w1.w * b1.w;
  s1 = wave_reduce_sum(s1);
  c = wave_reduce_sum(c);
  if (lane == 0) { *s1p = s1; *cp = c + extra_c; }
}

// ---------------------------------------------------------------------------
// Prep bundle: everything NOT needed before the qkv GEMM completes. These
// units ride as extra blockIdx.y rows of the qkv GEMM dispatch (1088 units),
// filling idle CU capacity (576 gemm blocks << ~2000 resident capacity).
// ---------------------------------------------------------------------------
struct PrepX {
  const float *eemb, *wekw, *wekb, *wevw, *wevb;     // edge tables
  const float *ln2w, *ln2b, *cfcw, *cfcb;            // fc LN-folded rows
  const float *wproj, *wcproj;                       // plain conversions
  float *ektab, *evtab, *s1f, *cf;
  bf16_t *wfc_bf, *wproj_bf, *wcproj_bf;
};

__device__ void prep_unit(int u, const PrepX& X, int tid) {
  int lane = tid & 63, wave = tid >> 6;
  if (u < 256) {
    // edge tables: wave per 16 outputs (wid = u*4+wave, 0..1023)
    int wid = u * 4 + wave;
    int gbase = wid * 16;
    int table = gbase >> 13;
    int e = (gbase >> 9) & 15;
    int c0 = gbase & 511;
    const float* er = X.eemb + e * 512 + lane * 8;
    f32x4 ea = *(const f32x4*)er;
    f32x4 eb = *(const f32x4*)(er + 4);
    const float* wbase = table ? X.wevw : X.wekw;
    const float* bbase = table ? X.wevb : X.wekb;
    float* obase = (table ? X.evtab : X.ektab) + e * 512;
#pragma unroll
    for (int o = 0; o < 16; o++) {
      int c = c0 + o;
      const float* wr = wbase + (size_t)c * 512 + lane * 8;
      f32x4 wa = *(const f32x4*)wr;
      f32x4 wb = *(const f32x4*)(wr + 4);
      float acc = ea.x * wa.x + ea.y * wa.y + ea.z * wa.z + ea.w * wa.w +
                  eb.x * wb.x + eb.y * wb.y + eb.z * wb.z + eb.w * wb.w;
      acc = wave_reduce_sum(acc);
      if (lane == 0) obase[c] = acc + bbase[c];
    }
  } else if (u < 768) {
    int n = (u - 256) * 4 + wave;  // 0..2047
    wrow_unit(X.cfcw + (size_t)n * 512, X.ln2w, X.ln2b, X.cfcb[n],
              X.wfc_bf + (size_t)n * 512, X.s1f + n, X.cf + n, lane);
  } else if (u < 1024) {
    int base = (u - 768) * 1024;  // wcproj: 262144 f32x4
    for (int t = tid; t < 1024; t += 256) {
      f32x4 a = *((const f32x4*)X.wcproj + base + t);
      bf16x4v o;
      o[0] = (bf16_t)a.x; o[1] = (bf16_t)a.y; o[2] = (bf16_t)a.z; o[3] = (bf16_t)a.w;
      *((bf16x4v*)X.wcproj_bf + base + t) = o;
    }
  } else if (u < 1088) {
    int base = (u - 1024) * 1024;  // wproj: 65536 f32x4
    for (int t = tid; t < 1024; t += 256) {
      f32x4 a = *((const f32x4*)X.wproj + base + t);
      bf16x4v o;
      o[0] = (bf16_t)a.x; o[1] = (bf16_t)a.y; o[2] = (bf16_t)a.z; o[3] = (bf16_t)a.w;
      *((bf16x4v*)X.wproj_bf + base + t) = o;
    }
  }
}

// ---------------------------------------------------------------------------
// pre_k (481 blocks): ONLY the true qkv-GEMM dependencies.
// [0,384) qkv W' rows; [384,480) x row stats; [480] zero x1 stat accumulators.
// ---------------------------------------------------------------------------
struct PreArgs {
  const float *x, *ln1w, *ln1b, *wattn, *wattnb;
  float *xmu, *xrs, *x1s1, *x1s2, *s1q, *cq;
  bf16_t* wqkv_bf;
};

__global__ __launch_bounds__(256) void pre_k(PreArgs P) {
  int b = blockIdx.x, tid = threadIdx.x, lane = tid & 63, wave = tid >> 6;
  if (b < 384) {
    int n = b * 4 + wave;  // 0..1535
    wrow_unit(P.wattn + (size_t)n * 512, P.ln1w, P.ln1b, P.wattnb[n],
              P.wqkv_bf + (size_t)n * 512, P.s1q + n, P.cq + n, lane);
  } else if (b < 480) {
    int r = (b - 384) * 4 + wave;  // 0..383
    const float* xr = P.x + (size_t)r * 512 + lane * 8;
    f32x4 a = *(const f32x4*)xr, c = *(const f32x4*)(xr + 4);
    float s = a.x + a.y + a.z + a.w + c.x + c.y + c.z + c.w;
    float q = a.x * a.x + a.y * a.y + a.z * a.z + a.w * a.w +
              c.x * c.x + c.y * c.y + c.z * c.z + c.w * c.w;
    s = wave_reduce_sum(s);
    q = wave_reduce_sum(q);
    if (lane == 0) {
      float mu = s * (1.0f / 512.0f);
      float var = q * (1.0f / 512.0f) - mu * mu;
      P.xmu[r] = mu;
      P.xrs[r] = rsqrtf(var + 1e-5f);
    }
  } else {
    for (int i = tid; i < 384; i += 256) { P.x1s1[i] = 0.f; P.x1s2[i] = 0.f; }
  }
}

// ---------------------------------------------------------------------------
// Split-K NT GEMM, 32x32 tile (R10 measured-best; 16x32 regressed R11).
// 4 waves each K/4; K-loop hoists 4 k-steps of loads before MFMA.
// MODE 0 (QKV): A=x f32; fused-LN epilogue ->bf16; by>=12 rows run prep_unit.
// MODE 1 (PROJ): A bf16, +bias +res ->f32, atomic row stats of result
// MODE 2 (FC):   A=x1 f32, row stats from S1/S2; fused-LN; gelu ->bf16
// MODE 3 (CPROJ):A bf16, +bias +res ->f32 (d_out)
// ---------------------------------------------------------------------------
template <int MODE>
__global__ __launch_bounds__(256) void gemm_k(
    const void* __restrict__ Aptr, const bf16_t* __restrict__ Wb,
    const float* __restrict__ e0, const float* __restrict__ e1,
    const float* __restrict__ e2, const float* __restrict__ e3,
    const float* __restrict__ res, void* __restrict__ out,
    float* __restrict__ st1, float* __restrict__ st2, int N, int K, PrepX X) {
  constexpr bool AF32 = (MODE == 0 || MODE == 2);
  constexpr int AW = AF32 ? 2 : 1;
  __shared__ float part[4][32][32];
  int tid = threadIdx.x;
  if (MODE == 0 && blockIdx.y >= 12) {
    prep_unit((blockIdx.y - 12) * gridDim.x + blockIdx.x, X, tid);
    return;
  }
  int lane = tid & 63, wave = tid >> 6;
  int m0 = blockIdx.y * 32, n0 = blockIdx.x * 32;
  int r16 = lane & 15, quad = lane >> 4;
  int kchunk = K >> 2, k0 = wave * kchunk;

  f32x4 acc[2][2];
  f32x4 zero = {0.f, 0.f, 0.f, 0.f};
#pragma unroll
  for (int i = 0; i < 2; i++)
#pragma unroll
    for (int j = 0; j < 2; j++) acc[i][j] = zero;

  const float* Af = (const float*)Aptr + (size_t)(m0 + r16) * K + k0 + quad * 8;
  const bf16_t* Ab = (const bf16_t*)Aptr + (size_t)(m0 + r16) * K + k0 + quad * 8;
  const bf16_t* Wp = Wb + (size_t)(n0 + r16) * K + k0 + quad * 8;

  for (int kb0 = 0; kb0 < kchunk; kb0 += 128) {  // 4 k-steps per group
    uint4 araw[4][2][AW];
    uint4 braw[4][2];
#pragma unroll
    for (int u = 0; u < 4; u++) {
      int kb = kb0 + u * 32;
#pragma unroll
      for (int t = 0; t < 2; t++) {
        if (AF32) {
          araw[u][t][0] = *(const uint4*)(Af + (size_t)t * 16 * K + kb);
          araw[u][t][1] = *(const uint4*)(Af + (size_t)t * 16 * K + kb + 4);
        } else {
          araw[u][t][0] = *(const uint4*)(Ab + (size_t)t * 16 * K + kb);
        }
        braw[u][t] = *(const uint4*)(Wp + (size_t)t * 16 * K + kb);
      }
    }
#pragma unroll
    for (int u = 0; u < 4; u++) {
      bf16x8 af[2], bfr[2];
#pragma unroll
      for (int t = 0; t < 2; t++) {
        if (AF32) {
          f32x4 a = *reinterpret_cast<const f32x4*>(&araw[u][t][0]);
          f32x4 c = *reinterpret_cast<const f32x4*>(&araw[u][t][1]);
          af[t][0] = (bf16_t)a.x; af[t][1] = (bf16_t)a.y;
          af[t][2] = (bf16_t)a.z; af[t][3] = (bf16_t)a.w;
          af[t][4] = (bf16_t)c.x; af[t][5] = (bf16_t)c.y;
          af[t][6] = (bf16_t)c.z; af[t][7] = (bf16_t)c.w;
        } else {
          af[t] = *reinterpret_cast<const bf16x8*>(&araw[u][t][0]);
        }
        bfr[t] = *reinterpret_cast<const bf16x8*>(&braw[u][t]);
      }
#pragma unroll
      for (int i = 0; i < 2; i++)
#pragma unroll
        for (int j = 0; j < 2; j++)
          acc[i][j] = __builtin_amdgcn_mfma_f32_16x16x32_bf16(af[i], bfr[j],
                                                              acc[i][j], 0, 0, 0);
    }
  }

#pragma unroll
  for (int i = 0; i < 2; i++)
#pragma unroll
    for (int j = 0; j < 2; j++)
#pragma unroll
      for (int r = 0; r < 4; r++)
        part[wave][i * 16 + quad * 4 + r][j * 16 + r16] = acc[i][j][r];
  __syncthreads();

  int row = tid >> 3, c4 = (tid & 7) * 4;
  f32x4 v = *(const f32x4*)&part[0][row][c4];
  v += *(const f32x4*)&part[1][row][c4];
  v += *(const f32x4*)&part[2][row][c4];
  v += *(const f32x4*)&part[3][row][c4];
  int grow = m0 + row, gcol = n0 + c4;

  if (MODE == 0 || MODE == 2) {
    float mu, rs;
    if (MODE == 0) {
      mu = e0[grow]; rs = e1[grow];
    } else {
      float S = e0[grow], Q = e1[grow];
      mu = S * (1.0f / 512.0f);
      float var = Q * (1.0f / 512.0f) - mu * mu;
      rs = rsqrtf(var + 1e-5f);
    }
    f32x4 s1v = *(const f32x4*)(e2 + gcol);
    f32x4 ccv = *(const f32x4*)(e3 + gcol);
#pragma unroll
    for (int t = 0; t < 4; t++) {
      float x = rs * (v[t] - mu * s1v[t]) + ccv[t];
      if (MODE == 2) x = 0.5f * x * (1.0f + erff(x * 0.70710678118654752f));
      v[t] = x;
    }
    bf16x4v o;
#pragma unroll
    for (int t = 0; t < 4; t++) o[t] = (bf16_t)v[t];
    *(bf16x4v*)((bf16_t*)out + (size_t)grow * N + gcol) = o;
  } else {
    v += *(const f32x4*)(e2 + gcol);  // bias
    v += *(const f32x4*)(res + (size_t)grow * N + gcol);
    *(f32x4*)((float*)out + (size_t)grow * N + gcol) = v;
    if (MODE == 1) {
      float sv = v.x + v.y + v.z + v.w;
      float qv = v.x * v.x + v.y * v.y + v.z * v.z + v.w * v.w;
      sv += __shfl_down(sv, 4, 8); qv += __shfl_down(qv, 4, 8);
      sv += __shfl_down(sv, 2, 8); qv += __shfl_down(qv, 2, 8);
      sv += __shfl_down(sv, 1, 8); qv += __shfl_down(qv, 1, 8);
      if ((tid & 7) == 0) {
        atomicAdd(st1 + grow, sv);
        atomicAdd(st2 + grow, qv);
      }
    }
  }
}

// ---------------------------------------------------------------------------
// Attention: one block per (query row i, head h), 3072 blocks, ascending i.
// No-max softmax (scores bounded: 0.02-scale weights), 2-deep PV. R10 exact
// form — measured best; do not touch without per-dispatch evidence.
// ---------------------------------------------------------------------------
__global__ __launch_bounds__(256) void attn_k(
    const bf16_t* __restrict__ qkv, const int* __restrict__ bias_matrix,
    const float* __restrict__ attn_bias_emb, const float* __restrict__ ek_tab,
    const float* __restrict__ ev_tab, bf16_t* __restrict__ ybuf) {
  __shared__ float s[TT];
  __shared__ int ebuf[TT];
  __shared__ float qe[EE][68];
  __shared__ float evh[EE * 64];
  __shared__ float red[4 * 64];
  __shared__ float absh[EE];
  __shared__ float scr[4];

  int i = blockIdx.x, h = blockIdx.y;
  int tid = threadIdx.x, lane = tid & 63, wave = tid >> 6;
  int n = i + 1;

  for (int j = tid; j < n; j += 256) ebuf[j] = bias_matrix[i * TT + j];
  if (tid < EE) absh[tid] = attn_bias_emb[tid * HH + h];
  for (int idx = tid; idx < EE * 64; idx += 256) {
    int e = idx >> 6, d = idx & 63;
    float qv = (float)qkv[(size_t)i * 1536 + h * 64 + d];
    qe[e][d] = qv * ek_tab[e * 512 + h * 64 + d];
    evh[idx] = ev_tab[e * 512 + h * 64 + d];
  }
  __syncthreads();

  // ---- scores + exp (no max pass), accumulate denominator
  float ls = 0.0f;
  for (int jl = tid; jl < n; jl += 256) {
    int e = ebuf[jl];
    const uint4* kp = (const uint4*)(qkv + (size_t)jl * 1536 + 512 + h * 64);
    uint4 kr[8];
#pragma unroll
    for (int dg = 0; dg < 8; dg++) kr[dg] = kp[dg];
    float acc = 0.f;
#pragma unroll
    for (int dg = 0; dg < 8; dg++) {
      bf16x8 kv = *reinterpret_cast<const bf16x8*>(&kr[dg]);
      f32x4 qa = *(const f32x4*)&qe[e][dg * 8];
      f32x4 qb = *(const f32x4*)&qe[e][dg * 8 + 4];
      acc += (float)kv[0] * qa.x + (float)kv[1] * qa.y + (float)kv[2] * qa.z +
             (float)kv[3] * qa.w + (float)kv[4] * qb.x + (float)kv[5] * qb.y +
             (float)kv[6] * qb.z + (float)kv[7] * qb.w;
    }
    float p = __expf(acc * 0.125f + absh[e]);
    s[jl] = p;
    ls += p;
  }
  ls = wave_reduce_sum(ls);
  if (lane == 0) scr[wave] = ls;
  __syncthreads();
  float inv = 1.0f / (scr[0] + scr[1] + scr[2] + scr[3]);

  // ---- PV: wave per j, lane per d (2-deep — measured best, R6)
  float acc = 0.0f;
  int j = wave;
  for (; j + 4 < n; j += 8) {
    int e0 = ebuf[j], e1 = ebuf[j + 4];
    float p0 = s[j], p1 = s[j + 4];
    float v0 = (float)qkv[(size_t)j * 1536 + 1024 + h * 64 + lane];
    float v1 = (float)qkv[(size_t)(j + 4) * 1536 + 1024 + h * 64 + lane];
    acc += p0 * v0 * evh[e0 * 64 + lane] + p1 * v1 * evh[e1 * 64 + lane];
  }
  for (; j < n; j += 4) {
    int e = ebuf[j];
    float vv = (float)qkv[(size_t)j * 1536 + 1024 + h * 64 + lane];
    acc += s[j] * vv * evh[e * 64 + lane];
  }
  red[wave * 64 + lane] = acc;
  __syncthreads();
  if (tid < 64) {
    float y = (red[tid] + red[64 + tid] + red[128 + tid] + red[192 + tid]) * inv;
    ybuf[(size_t)i * CC + h * 64 + tid] = (bf16_t)y;
  }
}

// ---------------------------------------------------------------------------
extern "C" void kernel_launch(void* const* d_in, const int* in_sizes, int n_in,
                              void* d_out, int out_size, void* d_ws,
                              size_t ws_size, hipStream_t stream) {
  const float* x = (const float*)d_in[0];
  const int* bias_mat = (const int*)d_in[1];

  char* wp = (char*)d_ws;
  float* ektab = (float*)wp;  wp += 16 * 512 * 4;
  float* evtab = (float*)wp;  wp += 16 * 512 * 4;
  float* xmu = (float*)wp;    wp += 384 * 4;
  float* xrs = (float*)wp;    wp += 384 * 4;
  float* x1s1 = (float*)wp;   wp += 384 * 4;
  float* x1s2 = (float*)wp;   wp += 384 * 4;
  float* s1q = (float*)wp;    wp += 1536 * 4;
  float* cq = (float*)wp;     wp += 1536 * 4;
  float* s1f = (float*)wp;    wp += 2048 * 4;
  float* cf = (float*)wp;     wp += 2048 * 4;
  float* x1 = (float*)wp;     wp += 384 * 512 * 4;
  bf16_t* wqkv_bf = (bf16_t*)wp;   wp += 1536 * 512 * 2;
  bf16_t* wfc_bf = (bf16_t*)wp;    wp += 2048 * 512 * 2;
  bf16_t* wproj_bf = (bf16_t*)wp;  wp += 512 * 512 * 2;
  bf16_t* wcproj_bf = (bf16_t*)wp; wp += 512 * 2048 * 2;
  bf16_t* qkv = (bf16_t*)wp;  wp += 384 * 1536 * 2;
  bf16_t* ybuf = (bf16_t*)wp; wp += 384 * 512 * 2;
  bf16_t* gbuf = (bf16_t*)wp; wp += 384 * 2048 * 2;

  PreArgs P;
  P.x = x;
  P.ln1w = (const float*)d_in[2];
  P.ln1b = (const float*)d_in[3];
  P.wattn = (const float*)d_in[4];
  P.wattnb = (const float*)d_in[5];
  P.xmu = xmu; P.xrs = xrs; P.x1s1 = x1s1; P.x1s2 = x1s2;
  P.s1q = s1q; P.cq = cq; P.wqkv_bf = wqkv_bf;

  PrepX X;
  X.eemb = (const float*)d_in[9];
  X.wekw = (const float*)d_in[10];
  X.wekb = (const float*)d_in[11];
  X.wevw = (const float*)d_in[12];
  X.wevb = (const float*)d_in[13];
  X.ln2w = (const float*)d_in[14];
  X.ln2b = (const float*)d_in[15];
  X.cfcw = (const float*)d_in[16];
  X.cfcb = (const float*)d_in[17];
  X.wproj = (const float*)d_in[6];
  X.wcproj = (const float*)d_in[18];
  X.ektab = ektab; X.evtab = evtab; X.s1f = s1f; X.cf = cf;
  X.wfc_bf = wfc_bf; X.wproj_bf = wproj_bf; X.wcproj_bf = wcproj_bf;

  // 1) qkv-GEMM dependencies only: qkv W' rows + x stats + stat zeroing
  pre_k<<<481, 256, 0, stream>>>(P);
  // 2) qkv = LN1(x) @ wattn^T + b (576 gemm blocks) + 1088 hidden prep units
  //    (edge tables, wfc rows, wproj/wcproj conversion) in by rows 12..34
  gemm_k<0><<<dim3(48, 35), 256, 0, stream>>>(x, wqkv_bf, xmu, xrs, s1q, cq,
                                              nullptr, qkv, nullptr, nullptr,
                                              1536, 512, X);
  // 3) attention (R10 exact form)
  attn_k<<<dim3(TT, HH), 256, 0, stream>>>(qkv, bias_mat,
                                           (const float*)d_in[8], ektab, evtab,
                                           ybuf);
  // 4) x1 = x + y @ wproj^T + b ; x1 row stats
  gemm_k<1><<<dim3(16, 12), 256, 0, stream>>>(
      ybuf, wproj_bf, nullptr, nullptr, (const float*)d_in[7], nullptr, x, x1,
      x1s1, x1s2, 512, 512, X);
  // 5) g = gelu(LN2(x1) @ cfc^T + b)
  gemm_k<2><<<dim3(64, 12), 256, 0, stream>>>(x1, wfc_bf, x1s1, x1s2, s1f, cf,
                                              nullptr, gbuf, nullptr, nullptr,
                                              2048, 512, X);
  // 6) out = x1 + g @ cproj^T + b
  gemm_k<3><<<dim3(16, 12), 256, 0, stream>>>(
      gbuf, wcproj_bf, nullptr, nullptr, (const float*)d_in[19], nullptr, x1,
      d_out, nullptr, nullptr, 512, 2048, X);
}

// Round 13
// 172.443 us; speedup vs baseline: 1.0463x; 1.0139x over previous
//
#include <hip/hip_runtime.h>
#include <math.h>

// Problem constants: B=1, T=384, C=512, H=8, D=64, E=16. Inputs/outputs f32.
#define TT 384
#define CC 512
#define HH 8
#define EE 16

typedef __bf16 bf16_t;
typedef __bf16 bf16x8 __attribute__((ext_vector_type(8)));
typedef __bf16 bf16x4v __attribute__((ext_vector_type(4)));
typedef float f32x4 __attribute__((ext_vector_type(4)));

__device__ __forceinline__ float wave_reduce_sum(float v) {
#pragma unroll
  for (int off = 32; off >= 1; off >>= 1) v += __shfl_xor(v, off, 64);
  return v;
}

// ---------------------------------------------------------------------------
// wrow_unit: one LN-folded weight row: W'[n]=g∘W[n] (bf16), s1[n]=Σ W'[n,k],
// c[n] = Σ b_k W[n,k] + extra
// ---------------------------------------------------------------------------
__device__ __forceinline__ void wrow_unit(const float* __restrict__ wr,
                                          const float* __restrict__ g,
                                          const float* __restrict__ bb,
                                          float extra_c, bf16_t* __restrict__ orow,
                                          float* __restrict__ s1p,
                                          float* __restrict__ cp, int lane) {
  const float* p = wr + lane * 8;
  f32x4 w0 = *(const f32x4*)p, w1 = *(const f32x4*)(p + 4);
  f32x4 g0 = *(const f32x4*)(g + lane * 8), g1 = *(const f32x4*)(g + lane * 8 + 4);
  f32x4 b0 = *(const f32x4*)(bb + lane * 8), b1 = *(const f32x4*)(bb + lane * 8 + 4);
  f32x4 p0 = w0 * g0, p1 = w1 * g1;
  bf16x8 o;
  o[0] = (bf16_t)p0.x; o[1] = (bf16_t)p0.y; o[2] = (bf16_t)p0.z; o[3] = (bf16_t)p0.w;
  o[4] = (bf16_t)p1.x; o[5] = (bf16_t)p1.y; o[6] = (bf16_t)p1.z; o[7] = (bf16_t)p1.w;
  *(bf16x8*)(orow + lane * 8) = o;
  float s1 = p0.x + p0.y + p0.z + p0.w + p1.x + p1.y + p1.z + p1.w;
  float c = w0.x * b0.x + w0.y * b0.y + w0.z * b0.z + w0.w * b0.w +
            w1.x * b1.x + w1.y * b1.y + w1.z * b1.z + w1.w * b1.w;
  s1 = wave_reduce_sum(s1);
  c = wave_reduce_sum(c);
  if (lane == 0) { *s1p = s1; *cp = c + extra_c; }
}

// ---------------------------------------------------------------------------
// Prep bundle (hidden in qkv dispatch rows by>=12; 1089 units):
// 0-255 edge tables; 256-767 wfc rows; 768-1023 wcproj conv; 1024-1087
// wproj conv; 1088 zero x1 stat accumulators.
// ---------------------------------------------------------------------------
struct PrepX {
  const float *eemb, *wekw, *wekb, *wevw, *wevb;
  const float *ln2w, *ln2b, *cfcw, *cfcb;
  const float *wproj, *wcproj;
  float *ektab, *evtab, *s1f, *cf, *x1s1, *x1s2;
  bf16_t *wfc_bf, *wproj_bf, *wcproj_bf;
};

__device__ void prep_unit(int u, const PrepX& X, int tid) {
  int lane = tid & 63, wave = tid >> 6;
  if (u < 256) {
    int wid = u * 4 + wave;
    int gbase = wid * 16;
    int table = gbase >> 13;
    int e = (gbase >> 9) & 15;
    int c0 = gbase & 511;
    const float* er = X.eemb + e * 512 + lane * 8;
    f32x4 ea = *(const f32x4*)er;
    f32x4 eb = *(const f32x4*)(er + 4);
    const float* wbase = table ? X.wevw : X.wekw;
    const float* bbase = table ? X.wevb : X.wekb;
    float* obase = (table ? X.evtab : X.ektab) + e * 512;
#pragma unroll
    for (int o = 0; o < 16; o++) {
      int c = c0 + o;
      const float* wr = wbase + (size_t)c * 512 + lane * 8;
      f32x4 wa = *(const f32x4*)wr;
      f32x4 wb = *(const f32x4*)(wr + 4);
      float acc = ea.x * wa.x + ea.y * wa.y + ea.z * wa.z + ea.w * wa.w +
                  eb.x * wb.x + eb.y * wb.y + eb.z * wb.z + eb.w * wb.w;
      acc = wave_reduce_sum(acc);
      if (lane == 0) obase[c] = acc + bbase[c];
    }
  } else if (u < 768) {
    int n = (u - 256) * 4 + wave;  // 0..2047
    wrow_unit(X.cfcw + (size_t)n * 512, X.ln2w, X.ln2b, X.cfcb[n],
              X.wfc_bf + (size_t)n * 512, X.s1f + n, X.cf + n, lane);
  } else if (u < 1024) {
    int base = (u - 768) * 1024;  // wcproj: 262144 f32x4
    for (int t = tid; t < 1024; t += 256) {
      f32x4 a = *((const f32x4*)X.wcproj + base + t);
      bf16x4v o;
      o[0] = (bf16_t)a.x; o[1] = (bf16_t)a.y; o[2] = (bf16_t)a.z; o[3] = (bf16_t)a.w;
      *((bf16x4v*)X.wcproj_bf + base + t) = o;
    }
  } else if (u < 1088) {
    int base = (u - 1024) * 1024;  // wproj: 65536 f32x4
    for (int t = tid; t < 1024; t += 256) {
      f32x4 a = *((const f32x4*)X.wproj + base + t);
      bf16x4v o;
      o[0] = (bf16_t)a.x; o[1] = (bf16_t)a.y; o[2] = (bf16_t)a.z; o[3] = (bf16_t)a.w;
      *((bf16x4v*)X.wproj_bf + base + t) = o;
    }
  } else if (u == 1088) {
    for (int i = tid; i < 384; i += 256) { X.x1s1[i] = 0.f; X.x1s2[i] = 0.f; }
  }
}

// ---------------------------------------------------------------------------
// qkv_k: SELF-CONTAINED qkv GEMM — no pre-pass dependency. Each 32x32 tile:
//  - loads raw f32 x and wattn, folds g∘W inline into the B fragment
//  - accumulates per-wave partials of row Σx/Σx² and col Σ(gW)/Σ(bW)
//    alongside the MFMA loop (operands already in registers)
//  - quad-shuffle + LDS reduce, epilogue applies rs·(acc−mu·s1)+c+bias.
// by>=12 rows run prep units (tables, wfc, wproj/wcproj, stat zeroing).
// ---------------------------------------------------------------------------
__global__ __launch_bounds__(256) void qkv_k(
    const float* __restrict__ x, const float* __restrict__ wattn,
    const float* __restrict__ ln1w, const float* __restrict__ ln1b,
    const float* __restrict__ wattnb, bf16_t* __restrict__ out, PrepX X) {
  int tid = threadIdx.x;
  if (blockIdx.y >= 12) {
    prep_unit((blockIdx.y - 12) * gridDim.x + blockIdx.x, X, tid);
    return;
  }
  __shared__ float part[4][32][32];  // 16 KB
  __shared__ float rst[2][4][32];    // [sx|sxx][wave][row]  1 KB
  __shared__ float wst[2][4][32];    // [s1|c ][wave][col]  1 KB
  int lane = tid & 63, wave = tid >> 6;
  int m0 = blockIdx.y * 32, n0 = blockIdx.x * 32;
  int r16 = lane & 15, quad = lane >> 4;
  int k0 = wave * 128;  // K=512, kchunk=128

  f32x4 acc[2][2];
  f32x4 zero = {0.f, 0.f, 0.f, 0.f};
#pragma unroll
  for (int i = 0; i < 2; i++)
#pragma unroll
    for (int j = 0; j < 2; j++) acc[i][j] = zero;

  const float* Af = x + (size_t)(m0 + r16) * 512 + k0 + quad * 8;
  const float* Wf = wattn + (size_t)(n0 + r16) * 512 + k0 + quad * 8;
  const float* gp = ln1w + k0 + quad * 8;
  const float* bp = ln1b + k0 + quad * 8;

  float sx[2] = {0.f, 0.f}, sxx[2] = {0.f, 0.f};
  float s1[2] = {0.f, 0.f}, cc[2] = {0.f, 0.f};

  for (int kb0 = 0; kb0 < 128; kb0 += 64) {  // 2 k-steps hoisted
    uint4 araw[2][2][2], wraw[2][2][2];
#pragma unroll
    for (int u = 0; u < 2; u++) {
      int kb = kb0 + u * 32;
#pragma unroll
      for (int t = 0; t < 2; t++) {
        araw[u][t][0] = *(const uint4*)(Af + (size_t)t * 16 * 512 + kb);
        araw[u][t][1] = *(const uint4*)(Af + (size_t)t * 16 * 512 + kb + 4);
        wraw[u][t][0] = *(const uint4*)(Wf + (size_t)t * 16 * 512 + kb);
        wraw[u][t][1] = *(const uint4*)(Wf + (size_t)t * 16 * 512 + kb + 4);
      }
    }
#pragma unroll
    for (int u = 0; u < 2; u++) {
      int kb = kb0 + u * 32;
      f32x4 g0 = *(const f32x4*)(gp + kb), g1 = *(const f32x4*)(gp + kb + 4);
      f32x4 b0 = *(const f32x4*)(bp + kb), b1 = *(const f32x4*)(bp + kb + 4);
      bf16x8 af[2], bfr[2];
#pragma unroll
      for (int t = 0; t < 2; t++) {
        f32x4 a0 = *reinterpret_cast<const f32x4*>(&araw[u][t][0]);
        f32x4 a1 = *reinterpret_cast<const f32x4*>(&araw[u][t][1]);
        af[t][0] = (bf16_t)a0.x; af[t][1] = (bf16_t)a0.y;
        af[t][2] = (bf16_t)a0.z; af[t][3] = (bf16_t)a0.w;
        af[t][4] = (bf16_t)a1.x; af[t][5] = (bf16_t)a1.y;
        af[t][6] = (bf16_t)a1.z; af[t][7] = (bf16_t)a1.w;
        sx[t] += a0.x + a0.y + a0.z + a0.w + a1.x + a1.y + a1.z + a1.w;
        sxx[t] += a0.x * a0.x + a0.y * a0.y + a0.z * a0.z + a0.w * a0.w +
                  a1.x * a1.x + a1.y * a1.y + a1.z * a1.z + a1.w * a1.w;
        f32x4 w0 = *reinterpret_cast<const f32x4*>(&wraw[u][t][0]);
        f32x4 w1 = *reinterpret_cast<const f32x4*>(&wraw[u][t][1]);
        f32x4 p0 = w0 * g0, p1 = w1 * g1;
        bfr[t][0] = (bf16_t)p0.x; bfr[t][1] = (bf16_t)p0.y;
        bfr[t][2] = (bf16_t)p0.z; bfr[t][3] = (bf16_t)p0.w;
        bfr[t][4] = (bf16_t)p1.x; bfr[t][5] = (bf16_t)p1.y;
        bfr[t][6] = (bf16_t)p1.z; bfr[t][7] = (bf16_t)p1.w;
        s1[t] += p0.x + p0.y + p0.z + p0.w + p1.x + p1.y + p1.z + p1.w;
        cc[t] += w0.x * b0.x + w0.y * b0.y + w0.z * b0.z + w0.w * b0.w +
                 w1.x * b1.x + w1.y * b1.y + w1.z * b1.z + w1.w * b1.w;
      }
#pragma unroll
      for (int i = 0; i < 2; i++)
#pragma unroll
        for (int j = 0; j < 2; j++)
          acc[i][j] = __builtin_amdgcn_mfma_f32_16x16x32_bf16(af[i], bfr[j],
                                                              acc[i][j], 0, 0, 0);
    }
  }

  // quad-reduce stats (lanes r16, r16+16, r16+32, r16+48 → same value)
#pragma unroll
  for (int t = 0; t < 2; t++) {
    sx[t] += __shfl_xor(sx[t], 16, 64);  sx[t] += __shfl_xor(sx[t], 32, 64);
    sxx[t] += __shfl_xor(sxx[t], 16, 64); sxx[t] += __shfl_xor(sxx[t], 32, 64);
    s1[t] += __shfl_xor(s1[t], 16, 64);  s1[t] += __shfl_xor(s1[t], 32, 64);
    cc[t] += __shfl_xor(cc[t], 16, 64);  cc[t] += __shfl_xor(cc[t], 32, 64);
  }
  if (quad == 0) {
#pragma unroll
    for (int t = 0; t < 2; t++) {
      rst[0][wave][t * 16 + r16] = sx[t];
      rst[1][wave][t * 16 + r16] = sxx[t];
      wst[0][wave][t * 16 + r16] = s1[t];
      wst[1][wave][t * 16 + r16] = cc[t];
    }
  }
#pragma unroll
  for (int i = 0; i < 2; i++)
#pragma unroll
    for (int j = 0; j < 2; j++)
#pragma unroll
      for (int r = 0; r < 4; r++)
        part[wave][i * 16 + quad * 4 + r][j * 16 + r16] = acc[i][j][r];
  __syncthreads();

  int row = tid >> 3, c4 = (tid & 7) * 4;
  f32x4 v = *(const f32x4*)&part[0][row][c4];
  v += *(const f32x4*)&part[1][row][c4];
  v += *(const f32x4*)&part[2][row][c4];
  v += *(const f32x4*)&part[3][row][c4];
  float sxt = rst[0][0][row] + rst[0][1][row] + rst[0][2][row] + rst[0][3][row];
  float sxxt = rst[1][0][row] + rst[1][1][row] + rst[1][2][row] + rst[1][3][row];
  float mu = sxt * (1.0f / 512.0f);
  float var = sxxt * (1.0f / 512.0f) - mu * mu;
  float rs = rsqrtf(var + 1e-5f);
  int grow = m0 + row, gcol = n0 + c4;
  bf16x4v o;
#pragma unroll
  for (int t = 0; t < 4; t++) {
    int cl = c4 + t;
    float s1v = wst[0][0][cl] + wst[0][1][cl] + wst[0][2][cl] + wst[0][3][cl];
    float ccv = wst[1][0][cl] + wst[1][1][cl] + wst[1][2][cl] + wst[1][3][cl] +
                wattnb[n0 + cl];
    o[t] = (bf16_t)(rs * (v[t] - mu * s1v) + ccv);
  }
  *(bf16x4v*)(out + (size_t)grow * 1536 + gcol) = o;
}

// ---------------------------------------------------------------------------
// Split-K NT GEMM, 32x32 tile (R10 measured-best). 4 waves each K/4;
// K-loop hoists 4 k-steps of loads before MFMA.
// MODE 1 (PROJ): A bf16, +bias +res ->f32, atomic row stats of result
// MODE 2 (FC):   A=x1 f32, row stats from S1/S2; fused-LN; gelu ->bf16
// MODE 3 (CPROJ):A bf16, +bias +res ->f32 (d_out)
// ---------------------------------------------------------------------------
template <int MODE>
__global__ __launch_bounds__(256) void gemm_k(
    const void* __restrict__ Aptr, const bf16_t* __restrict__ Wb,
    const float* __restrict__ e0, const float* __restrict__ e1,
    const float* __restrict__ e2, const float* __restrict__ e3,
    const float* __restrict__ res, void* __restrict__ out,
    float* __restrict__ st1, float* __restrict__ st2, int N, int K) {
  constexpr bool AF32 = (MODE == 2);
  constexpr int AW = AF32 ? 2 : 1;
  __shared__ float part[4][32][32];
  int tid = threadIdx.x;
  int lane = tid & 63, wave = tid >> 6;
  int m0 = blockIdx.y * 32, n0 = blockIdx.x * 32;
  int r16 = lane & 15, quad = lane >> 4;
  int kchunk = K >> 2, k0 = wave * kchunk;

  f32x4 acc[2][2];
  f32x4 zero = {0.f, 0.f, 0.f, 0.f};
#pragma unroll
  for (int i = 0; i < 2; i++)
#pragma unroll
    for (int j = 0; j < 2; j++) acc[i][j] = zero;

  const float* Af = (const float*)Aptr + (size_t)(m0 + r16) * K + k0 + quad * 8;
  const bf16_t* Ab = (const bf16_t*)Aptr + (size_t)(m0 + r16) * K + k0 + quad * 8;
  const bf16_t* Wp = Wb + (size_t)(n0 + r16) * K + k0 + quad * 8;

  for (int kb0 = 0; kb0 < kchunk; kb0 += 128) {
    uint4 araw[4][2][AW];
    uint4 braw[4][2];
#pragma unroll
    for (int u = 0; u < 4; u++) {
      int kb = kb0 + u * 32;
#pragma unroll
      for (int t = 0; t < 2; t++) {
        if (AF32) {
          araw[u][t][0] = *(const uint4*)(Af + (size_t)t * 16 * K + kb);
          araw[u][t][1] = *(const uint4*)(Af + (size_t)t * 16 * K + kb + 4);
        } else {
          araw[u][t][0] = *(const uint4*)(Ab + (size_t)t * 16 * K + kb);
        }
        braw[u][t] = *(const uint4*)(Wp + (size_t)t * 16 * K + kb);
      }
    }
#pragma unroll
    for (int u = 0; u < 4; u++) {
      bf16x8 af[2], bfr[2];
#pragma unroll
      for (int t = 0; t < 2; t++) {
        if (AF32) {
          f32x4 a = *reinterpret_cast<const f32x4*>(&araw[u][t][0]);
          f32x4 c = *reinterpret_cast<const f32x4*>(&araw[u][t][1]);
          af[t][0] = (bf16_t)a.x; af[t][1] = (bf16_t)a.y;
          af[t][2] = (bf16_t)a.z; af[t][3] = (bf16_t)a.w;
          af[t][4] = (bf16_t)c.x; af[t][5] = (bf16_t)c.y;
          af[t][6] = (bf16_t)c.z; af[t][7] = (bf16_t)c.w;
        } else {
          af[t] = *reinterpret_cast<const bf16x8*>(&araw[u][t][0]);
        }
        bfr[t] = *reinterpret_cast<const bf16x8*>(&braw[u][t]);
      }
#pragma unroll
      for (int i = 0; i < 2; i++)
#pragma unroll
        for (int j = 0; j < 2; j++)
          acc[i][j] = __builtin_amdgcn_mfma_f32_16x16x32_bf16(af[i], bfr[j],
                                                              acc[i][j], 0, 0, 0);
    }
  }

#pragma unroll
  for (int i = 0; i < 2; i++)
#pragma unroll
    for (int j = 0; j < 2; j++)
#pragma unroll
      for (int r = 0; r < 4; r++)
        part[wave][i * 16 + quad * 4 + r][j * 16 + r16] = acc[i][j][r];
  __syncthreads();

  int row = tid >> 3, c4 = (tid & 7) * 4;
  f32x4 v = *(const f32x4*)&part[0][row][c4];
  v += *(const f32x4*)&part[1][row][c4];
  v += *(const f32x4*)&part[2][row][c4];
  v += *(const f32x4*)&part[3][row][c4];
  int grow = m0 + row, gcol = n0 + c4;

  if (MODE == 2) {
    float S = e0[grow], Q = e1[grow];
    float mu = S * (1.0f / 512.0f);
    float var = Q * (1.0f / 512.0f) - mu * mu;
    float rs = rsqrtf(var + 1e-5f);
    f32x4 s1v = *(const f32x4*)(e2 + gcol);
    f32x4 ccv = *(const f32x4*)(e3 + gcol);
    bf16x4v o;
#pragma unroll
    for (int t = 0; t < 4; t++) {
      float xg = rs * (v[t] - mu * s1v[t]) + ccv[t];
      xg = 0.5f * xg * (1.0f + erff(xg * 0.70710678118654752f));
      o[t] = (bf16_t)xg;
    }
    *(bf16x4v*)((bf16_t*)out + (size_t)grow * N + gcol) = o;
  } else {
    v += *(const f32x4*)(e2 + gcol);  // bias
    v += *(const f32x4*)(res + (size_t)grow * N + gcol);
    *(f32x4*)((float*)out + (size_t)grow * N + gcol) = v;
    if (MODE == 1) {
      float sv = v.x + v.y + v.z + v.w;
      float qv = v.x * v.x + v.y * v.y + v.z * v.z + v.w * v.w;
      sv += __shfl_down(sv, 4, 8); qv += __shfl_down(qv, 4, 8);
      sv += __shfl_down(sv, 2, 8); qv += __shfl_down(qv, 2, 8);
      sv += __shfl_down(sv, 1, 8); qv += __shfl_down(qv, 1, 8);
      if ((tid & 7) == 0) {
        atomicAdd(st1 + grow, sv);
        atomicAdd(st2 + grow, qv);
      }
    }
  }
}

// ---------------------------------------------------------------------------
// Attention: one block per (query row i, head h), 3072 blocks, ascending i.
// No-max softmax, 2-deep PV. R10 exact form — measured best; do not touch.
// ---------------------------------------------------------------------------
__global__ __launch_bounds__(256) void attn_k(
    const bf16_t* __restrict__ qkv, const int* __restrict__ bias_matrix,
    const float* __restrict__ attn_bias_emb, const float* __restrict__ ek_tab,
    const float* __restrict__ ev_tab, bf16_t* __restrict__ ybuf) {
  __shared__ float s[TT];
  __shared__ int ebuf[TT];
  __shared__ float qe[EE][68];
  __shared__ float evh[EE * 64];
  __shared__ float red[4 * 64];
  __shared__ float absh[EE];
  __shared__ float scr[4];

  int i = blockIdx.x, h = blockIdx.y;
  int tid = threadIdx.x, lane = tid & 63, wave = tid >> 6;
  int n = i + 1;

  for (int j = tid; j < n; j += 256) ebuf[j] = bias_matrix[i * TT + j];
  if (tid < EE) absh[tid] = attn_bias_emb[tid * HH + h];
  for (int idx = tid; idx < EE * 64; idx += 256) {
    int e = idx >> 6, d = idx & 63;
    float qv = (float)qkv[(size_t)i * 1536 + h * 64 + d];
    qe[e][d] = qv * ek_tab[e * 512 + h * 64 + d];
    evh[idx] = ev_tab[e * 512 + h * 64 + d];
  }
  __syncthreads();

  float ls = 0.0f;
  for (int jl = tid; jl < n; jl += 256) {
    int e = ebuf[jl];
    const uint4* kp = (const uint4*)(qkv + (size_t)jl * 1536 + 512 + h * 64);
    uint4 kr[8];
#pragma unroll
    for (int dg = 0; dg < 8; dg++) kr[dg] = kp[dg];
    float acc = 0.f;
#pragma unroll
    for (int dg = 0; dg < 8; dg++) {
      bf16x8 kv = *reinterpret_cast<const bf16x8*>(&kr[dg]);
      f32x4 qa = *(const f32x4*)&qe[e][dg * 8];
      f32x4 qb = *(const f32x4*)&qe[e][dg * 8 + 4];
      acc += (float)kv[0] * qa.x + (float)kv[1] * qa.y + (float)kv[2] * qa.z +
             (float)kv[3] * qa.w + (float)kv[4] * qb.x + (float)kv[5] * qb.y +
             (float)kv[6] * qb.z + (float)kv[7] * qb.w;
    }
    float p = __expf(acc * 0.125f + absh[e]);
    s[jl] = p;
    ls += p;
  }
  ls = wave_reduce_sum(ls);
  if (lane == 0) scr[wave] = ls;
  __syncthreads();
  float inv = 1.0f / (scr[0] + scr[1] + scr[2] + scr[3]);

  float acc = 0.0f;
  int j = wave;
  for (; j + 4 < n; j += 8) {
    int e0 = ebuf[j], e1 = ebuf[j + 4];
    float p0 = s[j], p1 = s[j + 4];
    float v0 = (float)qkv[(size_t)j * 1536 + 1024 + h * 64 + lane];
    float v1 = (float)qkv[(size_t)(j + 4) * 1536 + 1024 + h * 64 + lane];
    acc += p0 * v0 * evh[e0 * 64 + lane] + p1 * v1 * evh[e1 * 64 + lane];
  }
  for (; j < n; j += 4) {
    int e = ebuf[j];
    float vv = (float)qkv[(size_t)j * 1536 + 1024 + h * 64 + lane];
    acc += s[j] * vv * evh[e * 64 + lane];
  }
  red[wave * 64 + lane] = acc;
  __syncthreads();
  if (tid < 64) {
    float y = (red[tid] + red[64 + tid] + red[128 + tid] + red[192 + tid]) * inv;
    ybuf[(size_t)i * CC + h * 64 + tid] = (bf16_t)y;
  }
}

// ---------------------------------------------------------------------------
extern "C" void kernel_launch(void* const* d_in, const int* in_sizes, int n_in,
                              void* d_out, int out_size, void* d_ws,
                              size_t ws_size, hipStream_t stream) {
  const float* x = (const float*)d_in[0];
  const int* bias_mat = (const int*)d_in[1];

  char* wp = (char*)d_ws;
  float* ektab = (float*)wp;  wp += 16 * 512 * 4;
  float* evtab = (float*)wp;  wp += 16 * 512 * 4;
  float* x1s1 = (float*)wp;   wp += 384 * 4;
  float* x1s2 = (float*)wp;   wp += 384 * 4;
  float* s1f = (float*)wp;    wp += 2048 * 4;
  float* cf = (float*)wp;     wp += 2048 * 4;
  float* x1 = (float*)wp;     wp += 384 * 512 * 4;
  bf16_t* wfc_bf = (bf16_t*)wp;    wp += 2048 * 512 * 2;
  bf16_t* wproj_bf = (bf16_t*)wp;  wp += 512 * 512 * 2;
  bf16_t* wcproj_bf = (bf16_t*)wp; wp += 512 * 2048 * 2;
  bf16_t* qkv = (bf16_t*)wp;  wp += 384 * 1536 * 2;
  bf16_t* ybuf = (bf16_t*)wp; wp += 384 * 512 * 2;
  bf16_t* gbuf = (bf16_t*)wp; wp += 384 * 2048 * 2;

  PrepX X;
  X.eemb = (const float*)d_in[9];
  X.wekw = (const float*)d_in[10];
  X.wekb = (const float*)d_in[11];
  X.wevw = (const float*)d_in[12];
  X.wevb = (const float*)d_in[13];
  X.ln2w = (const float*)d_in[14];
  X.ln2b = (const float*)d_in[15];
  X.cfcw = (const float*)d_in[16];
  X.cfcb = (const float*)d_in[17];
  X.wproj = (const float*)d_in[6];
  X.wcproj = (const float*)d_in[18];
  X.ektab = ektab; X.evtab = evtab; X.s1f = s1f; X.cf = cf;
  X.x1s1 = x1s1; X.x1s2 = x1s2;
  X.wfc_bf = wfc_bf; X.wproj_bf = wproj_bf; X.wcproj_bf = wcproj_bf;

  // 1) self-contained qkv (576 gemm tiles, rows 0-11) + 1089 hidden prep
  //    units (rows 12-34): edge tables, wfc rows, wproj/wcproj, stat zeroing
  qkv_k<<<dim3(48, 35), 256, 0, stream>>>(
      x, (const float*)d_in[4], (const float*)d_in[2], (const float*)d_in[3],
      (const float*)d_in[5], qkv, X);
  // 2) attention (R10 exact form)
  attn_k<<<dim3(TT, HH), 256, 0, stream>>>(qkv, bias_mat,
                                           (const float*)d_in[8], ektab, evtab,
                                           ybuf);
  // 3) x1 = x + y @ wproj^T + b ; x1 row stats
  gemm_k<1><<<dim3(16, 12), 256, 0, stream>>>(
      ybuf, wproj_bf, nullptr, nullptr, (const float*)d_in[7], nullptr, x, x1,
      x1s1, x1s2, 512, 512);
  // 4) g = gelu(LN2(x1) @ cfc^T + b)
  gemm_k<2><<<dim3(64, 12), 256, 0, stream>>>(x1, wfc_bf, x1s1, x1s2, s1f, cf,
                                              nullptr, gbuf, nullptr, nullptr,
                                              2048, 512);
  // 5) out = x1 + g @ cproj^T + b
  gemm_k<3><<<dim3(16, 12), 256, 0, stream>>>(
      gbuf, wcproj_bf, nullptr, nullptr, (const float*)d_in[19], nullptr, x1,
      d_out, nullptr, nullptr, 512, 2048);
}